// Round 1
// baseline (266.012 us; speedup 1.0000x reference)
//
#include <hip/hip_runtime.h>

#define BB 16
#define TT 64
#define SS 256
#define DD 512

// fast tanh: 1 - 2/(e^{2x}+1); saturates to +/-1 for large |x|, no NaN.
__device__ __forceinline__ float fast_tanh(float x) {
    float e = __expf(2.0f * x);
    float r = __builtin_amdgcn_rcpf(e + 1.0f);
    return 1.0f - 2.0f * r;
}

// C[m,n] = sum_k A[m,k] * Bm[n,k] (+ bias[n]); both operands K-contiguous (A @ B^T).
// TRANS: store to ((m%TT)*BB + m/TT)*N + n  (i.e. (T,B,N) layout from m=b*T+t rows).
template <int HAS_BIAS, int TRANS>
__global__ __launch_bounds__(256) void gemm_abt(const float* __restrict__ A,
                                                const float* __restrict__ Bm,
                                                const float* __restrict__ bias,
                                                float* __restrict__ C,
                                                int M, int N, int K) {
    // 64x64 tile, BK=16, 256 threads, 4x4 per thread. LDS stored transposed [k][m]
    // with row pad 68 floats (16B-aligned rows, conflict-free float4 reads).
    __shared__ float As[16][68];
    __shared__ float Bs[16][68];
    const int tid = threadIdx.x;
    const int m0 = blockIdx.y * 64;
    const int n0 = blockIdx.x * 64;
    const int tx = tid & 15;
    const int ty = tid >> 4;
    const int lr = tid >> 2;        // 0..63
    const int lc = (tid & 3) << 2;  // 0,4,8,12
    float acc[4][4] = {};
    const float* Ap = A + (size_t)(m0 + lr) * K + lc;
    const float* Bp = Bm + (size_t)(n0 + lr) * K + lc;
    for (int k0 = 0; k0 < K; k0 += 16) {
        float4 a = *(const float4*)(Ap + k0);
        float4 b = *(const float4*)(Bp + k0);
        As[lc + 0][lr] = a.x; As[lc + 1][lr] = a.y; As[lc + 2][lr] = a.z; As[lc + 3][lr] = a.w;
        Bs[lc + 0][lr] = b.x; Bs[lc + 1][lr] = b.y; Bs[lc + 2][lr] = b.z; Bs[lc + 3][lr] = b.w;
        __syncthreads();
#pragma unroll
        for (int k = 0; k < 16; ++k) {
            float4 av = *(const float4*)&As[k][ty * 4];
            float4 bv = *(const float4*)&Bs[k][tx * 4];
            float am[4] = {av.x, av.y, av.z, av.w};
            float bn[4] = {bv.x, bv.y, bv.z, bv.w};
#pragma unroll
            for (int i = 0; i < 4; ++i)
#pragma unroll
                for (int j = 0; j < 4; ++j) acc[i][j] += am[i] * bn[j];
        }
        __syncthreads();
    }
#pragma unroll
    for (int i = 0; i < 4; ++i) {
        int m = m0 + ty * 4 + i;
#pragma unroll
        for (int j = 0; j < 4; ++j) {
            int n = n0 + tx * 4 + j;
            float val = acc[i][j];
            if (HAS_BIAS) val += bias[n];
            size_t idx;
            if (TRANS) {
                int bb = m / TT, t = m % TT;
                idx = ((size_t)t * BB + bb) * N + n;
            } else {
                idx = (size_t)m * N + n;
            }
            C[idx] = val;
        }
    }
}

// One block per (b,t). Computes align scores (134M tanh total across grid),
// sparsemax via bisection, writes align output (T,B,S), computes context
// c = p @ memory_bank, writes [c, source] into concat buffer.
__global__ __launch_bounds__(256) void align_kernel(const float* __restrict__ wq,
                                                    const float* __restrict__ uh,
                                                    const float* __restrict__ mb,
                                                    const int* __restrict__ mask,
                                                    const float* __restrict__ v,
                                                    const float* __restrict__ src,
                                                    float* __restrict__ align_out,
                                                    float* __restrict__ concat) {
    const int bt = blockIdx.x;
    const int b = bt / TT;
    const int t = bt % TT;
    const int tid = threadIdx.x;
    const int lane = tid & 63;
    const int wave = tid >> 6;
    __shared__ float zs[SS];

    // Per-lane fragments of wq row and v: lane handles d = lane*8 .. lane*8+7
    const float* wqp = wq + (size_t)bt * DD + lane * 8;
    const float* vp = v + lane * 8;
    float4 w0 = *(const float4*)wqp;
    float4 w1 = *(const float4*)(wqp + 4);
    float4 v0 = *(const float4*)vp;
    float4 v1 = *(const float4*)(vp + 4);
    float wr[8] = {w0.x, w0.y, w0.z, w0.w, w1.x, w1.y, w1.z, w1.w};
    float vr[8] = {v0.x, v0.y, v0.z, v0.w, v1.x, v1.y, v1.z, v1.w};

    const float* uhb = uh + (size_t)b * SS * DD;
    for (int s = wave; s < SS; s += 4) {
        const float* up = uhb + (size_t)s * DD + lane * 8;
        float4 u0 = *(const float4*)up;
        float4 u1 = *(const float4*)(up + 4);
        float uu[8] = {u0.x, u0.y, u0.z, u0.w, u1.x, u1.y, u1.z, u1.w};
        float p = 0.f;
#pragma unroll
        for (int j = 0; j < 8; ++j) p += vr[j] * fast_tanh(wr[j] + uu[j]);
#pragma unroll
        for (int off = 32; off > 0; off >>= 1) p += __shfl_xor(p, off, 64);
        if (lane == 0) zs[s] = (mask[b * SS + s] != 0) ? p : -1e9f;
    }
    __syncthreads();

    // Sparsemax over 256 scores: wave 0 only (shuffle-only reductions, no barriers).
    if (wave == 0) {
        float z0 = zs[lane];
        float z1 = zs[lane + 64];
        float z2 = zs[lane + 128];
        float z3 = zs[lane + 192];
        float mx = fmaxf(fmaxf(z0, z1), fmaxf(z2, z3));
#pragma unroll
        for (int off = 32; off > 0; off >>= 1) mx = fmaxf(mx, __shfl_xor(mx, off, 64));
        z0 -= mx; z1 -= mx; z2 -= mx; z3 -= mx;
        // Solve sum_i relu(z_i - tau) = 1 for tau in [-1, 0] by bisection.
        float lo = -1.0f, hi = 0.0f;
        for (int it = 0; it < 34; ++it) {
            float mid = 0.5f * (lo + hi);
            float ssum = fmaxf(z0 - mid, 0.f) + fmaxf(z1 - mid, 0.f) +
                         fmaxf(z2 - mid, 0.f) + fmaxf(z3 - mid, 0.f);
#pragma unroll
            for (int off = 32; off > 0; off >>= 1) ssum += __shfl_xor(ssum, off, 64);
            if (ssum >= 1.0f) lo = mid; else hi = mid;
        }
        float tau = 0.5f * (lo + hi);
        zs[lane] = fmaxf(z0 - tau, 0.f);
        zs[lane + 64] = fmaxf(z1 - tau, 0.f);
        zs[lane + 128] = fmaxf(z2 - tau, 0.f);
        zs[lane + 192] = fmaxf(z3 - tau, 0.f);
    }
    __syncthreads();

    // align_vectors output, (T,B,S) layout
    align_out[((size_t)t * BB + b) * SS + tid] = zs[tid];

    // c[d] = sum_s p[s] * mb[b,s,d]; thread owns d = tid and d = tid+256.
    // Block-uniform skip of zero rows (sparsemax support is small).
    const float* mbb = mb + (size_t)b * SS * DD;
    float acc0 = 0.f, acc1 = 0.f;
    for (int s = 0; s < SS; ++s) {
        float p = zs[s];
        if (p > 0.f) {
            acc0 += p * mbb[(size_t)s * DD + tid];
            acc1 += p * mbb[(size_t)s * DD + 256 + tid];
        }
    }
    float* crow = concat + (size_t)bt * (2 * DD);
    crow[tid] = acc0;
    crow[tid + 256] = acc1;
    // second half of concat = source row
    const float* srow = src + (size_t)bt * DD;
    crow[DD + tid] = srow[tid];
    crow[DD + 256 + tid] = srow[tid + 256];
}

extern "C" void kernel_launch(void* const* d_in, const int* in_sizes, int n_in,
                              void* d_out, int out_size, void* d_ws, size_t ws_size,
                              hipStream_t stream) {
    const float* source = (const float*)d_in[0];       // (B,T,D)
    const float* memory_bank = (const float*)d_in[1];  // (B,S,D)
    const int* memory_mask = (const int*)d_in[2];      // (B,S)
    const float* W_q = (const float*)d_in[3];          // (D,D)
    const float* b_q = (const float*)d_in[4];          // (D,)
    const float* W_c = (const float*)d_in[5];          // (D,D)
    const float* v = (const float*)d_in[6];            // (D,)
    const float* W_out = (const float*)d_in[7];        // (D,2D)
    const float* b_out = (const float*)d_in[8];        // (D,)

    float* out0 = (float*)d_out;                    // attn_h (T,B,D)
    float* out1 = out0 + (size_t)TT * BB * DD;      // align_vectors (T,B,S)

    float* wq = (float*)d_ws;                       // (B*T, D)   2 MB
    float* uh = wq + (size_t)BB * TT * DD;          // (B*S, D)   8 MB
    float* concat = uh + (size_t)BB * SS * DD;      // (B*T, 2D)  4 MB

    dim3 blk(256);
    // wq = source @ W_q^T + b_q
    gemm_abt<1, 0><<<dim3(DD / 64, BB * TT / 64), blk, 0, stream>>>(
        source, W_q, b_q, wq, BB * TT, DD, DD);
    // uh = memory_bank @ W_c^T
    gemm_abt<0, 0><<<dim3(DD / 64, BB * SS / 64), blk, 0, stream>>>(
        memory_bank, W_c, nullptr, uh, BB * SS, DD, DD);
    // fused align + sparsemax + context + concat
    align_kernel<<<dim3(BB * TT), blk, 0, stream>>>(
        wq, uh, memory_bank, memory_mask, v, source, out1, concat);
    // attn_h = concat @ W_out^T + b_out, stored (T,B,D)
    gemm_abt<1, 1><<<dim3(DD / 64, BB * TT / 64), blk, 0, stream>>>(
        concat, W_out, b_out, out0, BB * TT, DD, 2 * DD);
}

// Round 2
// 186.733 us; speedup vs baseline: 1.4246x; 1.4246x over previous
//
#include <hip/hip_runtime.h>
#include <hip/hip_bf16.h>

#define BB 16
#define TT 64
#define SS 256
#define DD 512

typedef __bf16 bf16x8 __attribute__((ext_vector_type(8)));
typedef float f32x4 __attribute__((ext_vector_type(4)));

__device__ __forceinline__ ushort f2b(float x) {
    __hip_bfloat16 h = __float2bfloat16(x);
    return __builtin_bit_cast(ushort, h);
}

// ---------------- fp32 -> bf16 cast of the 5 GEMM operands, one launch ----------
#define S_SRC (BB * TT * DD)   // 524288
#define S_MB  (BB * SS * DD)   // 2097152
#define S_WQ  (DD * DD)        // 262144
#define S_WC  (DD * DD)        // 262144
#define S_WO  (DD * 2 * DD)    // 524288

__global__ __launch_bounds__(256) void cast_all(
    const float* __restrict__ src, const float* __restrict__ mb,
    const float* __restrict__ wq, const float* __restrict__ wc,
    const float* __restrict__ wo,
    ushort* __restrict__ src_b, ushort* __restrict__ mb_b,
    ushort* __restrict__ wq_b, ushort* __restrict__ wc_b,
    ushort* __restrict__ wo_b) {
    int g = blockIdx.x * 256 + threadIdx.x;  // float4-group index
    const int G0 = S_SRC / 4, G1 = S_MB / 4, G2 = S_WQ / 4, G3 = S_WC / 4;
    const float* in;
    ushort* out;
    int local;
    if (g < G0) { in = src; out = src_b; local = g; }
    else if (g < G0 + G1) { in = mb; out = mb_b; local = g - G0; }
    else if (g < G0 + G1 + G2) { in = wq; out = wq_b; local = g - G0 - G1; }
    else if (g < G0 + G1 + G2 + G3) { in = wc; out = wc_b; local = g - G0 - G1 - G2; }
    else { in = wo; out = wo_b; local = g - G0 - G1 - G2 - G3; }
    float4 x = *(const float4*)(in + (size_t)local * 4);
    ushort4 y = {f2b(x.x), f2b(x.y), f2b(x.z), f2b(x.w)};
    *(ushort4*)(out + (size_t)local * 4) = y;
}

// ---------------- LDS-free MFMA GEMM: C[m,n] = sum_k A[m,k]*Bm[n,k] (+bias) -----
// Block 256 thr = 4 waves; block tile 32x64; wave tile 16x32 (2 MFMA 16x16x32).
// Fragments loaded straight from global (L2-hot; A rows reused across n-blocks,
// B rows across m-blocks). No LDS, no barriers.
// TRANS: row m = b*TT+t stored at ((t*BB)+b)*N + n. BATCH: z-batched B and C.
template <int K, int HAS_BIAS, int TRANS, int BATCH>
__global__ __launch_bounds__(256) void gemm_mfma(const ushort* __restrict__ A,
                                                 const ushort* __restrict__ Bm,
                                                 const float* __restrict__ bias,
                                                 float* __restrict__ C,
                                                 int M, int N) {
    const int tid = threadIdx.x;
    const int lane = tid & 63;
    const int wave = tid >> 6;
    const int wm = wave & 1, wn = wave >> 1;
    const int m0 = blockIdx.y * 32 + wm * 16;
    const int n0 = blockIdx.x * 64 + wn * 32;
    if (BATCH) {
        Bm += (size_t)blockIdx.z * SS * K;
        C += (size_t)blockIdx.z * (size_t)M * N;
    }
    const int l15 = lane & 15;
    const int kg = (lane >> 4) * 8;  // k-group base: A[m=lane&15][k=quad*8+j]
    const ushort* Ap = A + (size_t)(m0 + l15) * K + kg;
    const ushort* Bp0 = Bm + (size_t)(n0 + l15) * K + kg;
    const ushort* Bp1 = Bp0 + (size_t)16 * K;
    f32x4 acc0 = {0.f, 0.f, 0.f, 0.f}, acc1 = {0.f, 0.f, 0.f, 0.f};
#pragma unroll 4
    for (int k0 = 0; k0 < K; k0 += 32) {
        bf16x8 a = *(const bf16x8*)(Ap + k0);
        bf16x8 b0 = *(const bf16x8*)(Bp0 + k0);
        bf16x8 b1 = *(const bf16x8*)(Bp1 + k0);
        acc0 = __builtin_amdgcn_mfma_f32_16x16x32_bf16(a, b0, acc0, 0, 0, 0);
        acc1 = __builtin_amdgcn_mfma_f32_16x16x32_bf16(a, b1, acc1, 0, 0, 0);
    }
    // C/D layout: col = lane&15, row = (lane>>4)*4 + reg
#pragma unroll
    for (int r = 0; r < 4; ++r) {
        int m = m0 + (lane >> 4) * 4 + r;
        int n = n0 + l15;
        float v0 = acc0[r], v1 = acc1[r];
        if (HAS_BIAS) { v0 += bias[n]; v1 += bias[n + 16]; }
        size_t i0, i1;
        if (TRANS) {
            int bb = m >> 6, t = m & 63;  // m = b*64 + t
            size_t row = ((size_t)t * BB + bb) * N;
            i0 = row + n; i1 = row + n + 16;
        } else {
            i0 = (size_t)m * N + n; i1 = i0 + 16;
        }
        C[i0] = v0; C[i1] = v1;
    }
}

// ---------------- fused align + sparsemax + context + concat --------------------
// One block per (b,t); thread tid owns score s=tid (no cross-lane reduction).
// uhT is (B, D, S) so the inner-loop load is coalesced across s.
__global__ __launch_bounds__(256) void align2(const float* __restrict__ wq,
                                              const float* __restrict__ uhT,
                                              const float* __restrict__ mb,
                                              const int* __restrict__ mask,
                                              const float* __restrict__ v,
                                              const float* __restrict__ src,
                                              float* __restrict__ align_out,
                                              ushort* __restrict__ concat) {
    const int bt = blockIdx.x;
    const int b = bt >> 6, t = bt & 63;
    const int tid = threadIdx.x;
    const int lane = tid & 63;
    const int wave = tid >> 6;
    __shared__ float zs[SS];

    const float* wrow = wq + (size_t)bt * DD;   // wave-uniform (scalar loads)
    const float* ub = uhT + (size_t)b * DD * SS + tid;
    float p = 0.f;
#pragma unroll 8
    for (int d = 0; d < DD; ++d) {
        float u = ub[(size_t)d * SS];
        float s = wrow[d] + u;
        float e = __expf(2.0f * s);
        float r = __builtin_amdgcn_rcpf(e + 1.0f);
        float th = __builtin_fmaf(-2.0f, r, 1.0f);  // tanh = 1 - 2/(e^2x+1)
        p = __builtin_fmaf(v[d], th, p);
    }
    zs[tid] = (mask[b * SS + tid] != 0) ? p : -1e9f;
    __syncthreads();

    // Sparsemax over 256 scores: wave 0 only (shuffle-only, no barriers).
    if (wave == 0) {
        float z0 = zs[lane];
        float z1 = zs[lane + 64];
        float z2 = zs[lane + 128];
        float z3 = zs[lane + 192];
        float mx = fmaxf(fmaxf(z0, z1), fmaxf(z2, z3));
#pragma unroll
        for (int off = 32; off > 0; off >>= 1) mx = fmaxf(mx, __shfl_xor(mx, off, 64));
        z0 -= mx; z1 -= mx; z2 -= mx; z3 -= mx;
        // Solve sum_i relu(z_i - tau) = 1, tau in [-1, 0], by bisection.
        float lo = -1.0f, hi = 0.0f;
        for (int it = 0; it < 34; ++it) {
            float mid = 0.5f * (lo + hi);
            float ssum = fmaxf(z0 - mid, 0.f) + fmaxf(z1 - mid, 0.f) +
                         fmaxf(z2 - mid, 0.f) + fmaxf(z3 - mid, 0.f);
#pragma unroll
            for (int off = 32; off > 0; off >>= 1) ssum += __shfl_xor(ssum, off, 64);
            if (ssum >= 1.0f) lo = mid; else hi = mid;
        }
        float tau = 0.5f * (lo + hi);
        zs[lane] = fmaxf(z0 - tau, 0.f);
        zs[lane + 64] = fmaxf(z1 - tau, 0.f);
        zs[lane + 128] = fmaxf(z2 - tau, 0.f);
        zs[lane + 192] = fmaxf(z3 - tau, 0.f);
    }
    __syncthreads();

    align_out[((size_t)t * BB + b) * SS + tid] = zs[tid];

    // c[d] = sum_s p[s] * mb[b,s,d]; thread owns d = tid, tid+256.
    const float* mbb = mb + (size_t)b * SS * DD;
    float acc0 = 0.f, acc1 = 0.f;
    for (int s = 0; s < SS; ++s) {
        float ps = zs[s];
        if (ps > 0.f) {
            acc0 += ps * mbb[(size_t)s * DD + tid];
            acc1 += ps * mbb[(size_t)s * DD + 256 + tid];
        }
    }
    ushort* crow = concat + (size_t)bt * (2 * DD);
    crow[tid] = f2b(acc0);
    crow[tid + 256] = f2b(acc1);
    const float* srow = src + (size_t)bt * DD;
    crow[DD + tid] = f2b(srow[tid]);
    crow[DD + 256 + tid] = f2b(srow[tid + 256]);
}

extern "C" void kernel_launch(void* const* d_in, const int* in_sizes, int n_in,
                              void* d_out, int out_size, void* d_ws, size_t ws_size,
                              hipStream_t stream) {
    const float* source = (const float*)d_in[0];       // (B,T,D)
    const float* memory_bank = (const float*)d_in[1];  // (B,S,D)
    const int* memory_mask = (const int*)d_in[2];      // (B,S)
    const float* W_q = (const float*)d_in[3];          // (D,D)
    const float* b_q = (const float*)d_in[4];          // (D,)
    const float* W_c = (const float*)d_in[5];          // (D,D)
    const float* v = (const float*)d_in[6];            // (D,)
    const float* W_out = (const float*)d_in[7];        // (D,2D)
    const float* b_out = (const float*)d_in[8];        // (D,)

    float* out0 = (float*)d_out;                   // attn_h (T,B,D)
    float* out1 = out0 + (size_t)TT * BB * DD;     // align_vectors (T,B,S)

    // workspace layout (all 16B-aligned; ~19 MB total)
    float* wq_f = (float*)d_ws;                    // (B*T, D) fp32      2 MB
    float* uhT = wq_f + S_SRC;                     // (B, D, S) fp32     8 MB
    ushort* src_b = (ushort*)(uhT + S_MB);         // 1 MB
    ushort* mb_b = src_b + S_SRC;                  // 4 MB
    ushort* wqw_b = mb_b + S_MB;                   // 0.5 MB
    ushort* wcw_b = wqw_b + S_WQ;                  // 0.5 MB
    ushort* wo_b = wcw_b + S_WC;                   // 1 MB
    ushort* cc_b = wo_b + S_WO;                    // (B*T, 2D) bf16     2 MB

    dim3 blk(256);
    // 1. cast the 5 bf16 operands
    int ngroups = (S_SRC + S_MB + S_WQ + S_WC + S_WO) / 4;
    cast_all<<<dim3(ngroups / 256), blk, 0, stream>>>(
        source, memory_bank, W_q, W_c, W_out, src_b, mb_b, wqw_b, wcw_b, wo_b);
    // 2. wq = source @ W_q^T + b_q            (M=1024, N=512, K=512)
    gemm_mfma<DD, 1, 0, 0><<<dim3(DD / 64, BB * TT / 32), blk, 0, stream>>>(
        src_b, wqw_b, b_q, wq_f, BB * TT, DD);
    // 3. uhT[b] = W_c @ mb[b]^T               (M=512, N=256, K=512, batched over b)
    gemm_mfma<DD, 0, 0, 1><<<dim3(SS / 64, DD / 32, BB), blk, 0, stream>>>(
        wcw_b, mb_b, nullptr, uhT, DD, SS);
    // 4. fused align + sparsemax + context + concat
    align2<<<dim3(BB * TT), blk, 0, stream>>>(
        wq_f, uhT, memory_bank, memory_mask, v, source, out1, cc_b);
    // 5. attn_h = concat @ W_out^T + b_out, stored (T,B,D)   (M=1024, N=512, K=1024)
    gemm_mfma<2 * DD, 1, 1, 0><<<dim3(DD / 64, BB * TT / 32), blk, 0, stream>>>(
        cc_b, wo_b, b_out, out0, BB * TT, DD);
}